// Round 16
// baseline (756.796 us; speedup 1.0000x reference)
//
#include <hip/hip_runtime.h>
#include <cstddef>
#include <cstdint>

#define LEAKY_ATT 0.2f
#define LEAKY_ACT 0.01f
#define BN_EPS 1e-5f

typedef __attribute__((ext_vector_type(8))) short bf16x8;
typedef __attribute__((ext_vector_type(4))) float f32x4;
typedef __fp16 f16x2 __attribute__((ext_vector_type(2)));

// round-to-nearest-even f32 -> bf16
static __device__ __forceinline__ unsigned short f2bf(float f){
  unsigned u = __float_as_uint(f);
  unsigned r = u + 0x7fffu + ((u >> 16) & 1u);
  return (unsigned short)(r >> 16);
}
static __device__ __forceinline__ float bf_lo(unsigned u){ return __uint_as_float(u << 16); }
static __device__ __forceinline__ float bf_hi(unsigned u){ return __uint_as_float(u & 0xffff0000u); }
static __device__ __forceinline__ float bf2f(unsigned short u){ return __uint_as_float((unsigned)u << 16); }

static __device__ __forceinline__ f16x2 cvtpk(float a, float b){
#if __has_builtin(__builtin_amdgcn_cvt_pkrtz)
  return __builtin_amdgcn_cvt_pkrtz(a, b);
#else
  f16x2 r; r.x = (__fp16)a; r.y = (__fp16)b; return r;
#endif
}
#if __has_builtin(__builtin_amdgcn_fdot2)
#define FDOT2(a,b,c) __builtin_amdgcn_fdot2((a),(b),(c),false)
#else
static __device__ __forceinline__ float fdot2_emu(f16x2 a, f16x2 b, float c){
  return (float)a.x*(float)b.x + ((float)a.y*(float)b.y + c);
}
#define FDOT2(a,b,c) fdot2_emu((a),(b),(c))
#endif

static __device__ __forceinline__ f16x2 bcast_pair(f16x2 v, int k){
  int iv; __builtin_memcpy(&iv, &v, 4);
  iv = __shfl(iv, k);
  f16x2 r; __builtin_memcpy(&r, &iv, 4);
  return r;
}

// full-wave (64-lane) f32 sum via DPP row ops — VALU pipe only, no LDS.
static __device__ __forceinline__ float wave_sum64(float x){
  float t;
  t = __int_as_float(__builtin_amdgcn_update_dpp(0, __float_as_int(x), 0x111, 0xf, 0xf, true)); x += t;
  t = __int_as_float(__builtin_amdgcn_update_dpp(0, __float_as_int(x), 0x112, 0xf, 0xf, true)); x += t;
  t = __int_as_float(__builtin_amdgcn_update_dpp(0, __float_as_int(x), 0x114, 0xf, 0xf, true)); x += t;
  t = __int_as_float(__builtin_amdgcn_update_dpp(0, __float_as_int(x), 0x118, 0xf, 0xf, true)); x += t;
  t = __int_as_float(__builtin_amdgcn_update_dpp(0, __float_as_int(x), 0x142, 0xf, 0xf, true)); x += t; // row_bcast:15
  t = __int_as_float(__builtin_amdgcn_update_dpp(0, __float_as_int(x), 0x143, 0xf, 0xf, true)); x += t; // row_bcast:31
  return __int_as_float(__builtin_amdgcn_readlane(__float_as_int(x), 63));
}

// ------ merged prep: embed (blocks [0,768)) + deg (768..1024) + wprep -------
// The three jobs are independent; merging removes 5 serialized dispatches.
__global__ __launch_bounds__(256) void k_prep(
    const float* __restrict__ x, const float* __restrict__ emb,
    unsigned short* __restrict__ hb,
    const int* __restrict__ dst, int* __restrict__ deg,
    const float* __restrict__ Wl1, const float* __restrict__ Wr1,
    const float* __restrict__ Wl2, const float* __restrict__ Wr2,
    unsigned short* __restrict__ wt1l, unsigned short* __restrict__ wt1r,
    unsigned short* __restrict__ wt2l, unsigned short* __restrict__ wt2r,
    int N, int E)
{
  int b = blockIdx.x;
  if (b < 768){                    // ---- embed: argmax + bf16 lookup ----
    int wv = threadIdx.x >> 6, lane = threadIdx.x & 63;
    for (int n = b*4 + wv; n < N; n += 768*4){
      float v = x[(size_t)n*64 + lane];
      int idx = lane;
      #pragma unroll
      for (int off = 32; off; off >>= 1){
        float ov = __shfl_down(v, off);
        int   oi = __shfl_down(idx, off);
        if (ov > v || (ov == v && oi < idx)) { v = ov; idx = oi; }
      }
      idx = __shfl(idx, 0);
      hb[(size_t)n*128 + lane]      = f2bf(emb[(size_t)idx*128 + lane]);
      hb[(size_t)n*128 + 64 + lane] = f2bf(emb[(size_t)idx*128 + 64 + lane]);
    }
  } else if (b < 1024){            // ---- deg ----
    for (int e = (b-768)*256 + threadIdx.x; e < E; e += 256*256)
      atomicAdd(&deg[dst[e]], 1);
  } else {                         // ---- wprep ×4 (bf16 transpose) ----
    const int T1 = 128*128, T2 = 128*256;
    for (int i = (b-1024)*256 + threadIdx.x; i < 2*T1 + 2*T2; i += 64*256){
      int j = i; const float* W; unsigned short* Wt; int K = 128, C;
      if (j < T1)            { W = Wl1; Wt = wt1l; C = 128; }
      else if (j < 2*T1)     { j -= T1;   W = Wr1; Wt = wt1r; C = 128; }
      else if (j < 2*T1+T2)  { j -= 2*T1; W = Wl2; Wt = wt2l; C = 256; }
      else                   { j -= 2*T1+T2; W = Wr2; Wt = wt2r; C = 256; }
      int n = j / K, k = j - n*K;
      Wt[j] = f2bf(W[(size_t)k*C + n]);
    }
  }
}

// ---------------- hierarchical exclusive scan of (deg[i]+1) -----------------
__global__ __launch_bounds__(256) void k_scan1(const int* __restrict__ deg,
                        int* __restrict__ rowptr, int* __restrict__ bsum, int N){
  __shared__ int sd[256];
  int tid = threadIdx.x;
  int base = blockIdx.x*1024 + tid*4;
  int v0=0,v1=0,v2=0,v3=0;
  if (base+0 < N) v0 = deg[base+0]+1;
  if (base+1 < N) v1 = deg[base+1]+1;
  if (base+2 < N) v2 = deg[base+2]+1;
  if (base+3 < N) v3 = deg[base+3]+1;
  int t = v0+v1+v2+v3;
  sd[tid] = t;
  __syncthreads();
  for (int off = 1; off < 256; off <<= 1){
    int x = (tid >= off) ? sd[tid-off] : 0;
    __syncthreads();
    sd[tid] += x;
    __syncthreads();
  }
  int excl = sd[tid] - t;
  if (tid == 255) bsum[blockIdx.x] = sd[255];
  if (base+0 < N) rowptr[base+0] = excl;
  if (base+1 < N) rowptr[base+1] = excl + v0;
  if (base+2 < N) rowptr[base+2] = excl + v0 + v1;
  if (base+3 < N) rowptr[base+3] = excl + v0 + v1 + v2;
}
__global__ void k_scan2(int* __restrict__ bsum, int nb){
  int lane = threadIdx.x & 63;
  int carry = 0;
  for (int base = 0; base < nb; base += 64){
    int idx = base + lane;
    int v = (idx < nb) ? bsum[idx] : 0;
    int orig = v;
    #pragma unroll
    for (int off = 1; off < 64; off <<= 1){
      int x = __shfl_up(v, off);
      if (lane >= off) v += x;
    }
    if (idx < nb) bsum[idx] = carry + v - orig;   // exclusive
    carry += __shfl(v, 63);
  }
}
__global__ void k_scan3(int* __restrict__ rowptr, const int* __restrict__ bsum,
                        int N, int EP){
  int i = blockIdx.x*blockDim.x + threadIdx.x;
  if (i < N) rowptr[i] += bsum[i >> 10];
  if (i == N) rowptr[N] = EP;
}

// ---------------- CSR fill: store {src, edge_id} per slot -------------------
__global__ void k_csrfill(const int* __restrict__ src, const int* __restrict__ dst,
                          const int* __restrict__ rowptr,
                          int* __restrict__ cur, int2* __restrict__ csr2, int E, int N){
  int i = blockIdx.x*blockDim.x + threadIdx.x;
  if (i >= E + N) return;
  int d, s;
  if (i < E){ d = dst[i]; s = src[i]; }
  else      { d = i - E;  s = i - E;  }
  int pos = atomicAdd(&cur[d], 1);
  csr2[rowptr[d] + pos] = make_int2(s, i);
}

// ---------------- MFMA GEMM: [xl|xr] = A[N,128]bf16 @ Wt^T + bias -----------
template<bool APPLY_BN>
__global__ __launch_bounds__(256) void k_gemm_mfma(
    const unsigned short* __restrict__ A,
    const unsigned short* __restrict__ Wtl, const float* __restrict__ bl,
    const unsigned short* __restrict__ Wtr, const float* __restrict__ br,
    const float* __restrict__ bnsc, const float* __restrict__ bnsh,
    unsigned short* __restrict__ xlb, float* __restrict__ xr,
    int N, int C)
{
  constexpr int K = 128;
  __shared__ unsigned short As[64][40];    // +8 bf16 pad: bank-conflict-free b128
  int tid = threadIdx.x;
  int wv = tid >> 6, lane = tid & 63;
  int m0 = blockIdx.x*64;
  int half = gridDim.y >> 1;
  bool isL = ((int)blockIdx.y < half);
  int n0 = (isL ? blockIdx.y : blockIdx.y - half) * 128;
  const unsigned short* Wt = isL ? Wtl : Wtr;
  const float* bias = isL ? bl : br;

  f32x4 acc[8];
  #pragma unroll
  for (int t = 0; t < 8; ++t) acc[t] = (f32x4){0.f,0.f,0.f,0.f};

  int srow = tid >> 2;            // 0..63
  int sseg = (tid & 3) * 8;       // k-offset 0,8,16,24
  int grow = m0 + srow;
  int arow = wv*16 + (lane & 15);
  int koff = (lane >> 4) * 8;

  for (int k0 = 0; k0 < K; k0 += 32){
    __syncthreads();
    uint4 raw = make_uint4(0,0,0,0);
    if (grow < N){
      raw = *reinterpret_cast<const uint4*>(&A[(size_t)grow*K + k0 + sseg]);
      if constexpr (APPLY_BN){
        float4 sa = *reinterpret_cast<const float4*>(&bnsc[k0 + sseg]);
        float4 sb = *reinterpret_cast<const float4*>(&bnsc[k0 + sseg + 4]);
        float4 ha = *reinterpret_cast<const float4*>(&bnsh[k0 + sseg]);
        float4 hb = *reinterpret_cast<const float4*>(&bnsh[k0 + sseg + 4]);
        float f0 = bf_lo(raw.x)*sa.x + ha.x; f0 = (f0>=0.f)?f0:LEAKY_ACT*f0;
        float f1 = bf_hi(raw.x)*sa.y + ha.y; f1 = (f1>=0.f)?f1:LEAKY_ACT*f1;
        float f2 = bf_lo(raw.y)*sa.z + ha.z; f2 = (f2>=0.f)?f2:LEAKY_ACT*f2;
        float f3 = bf_hi(raw.y)*sa.w + ha.w; f3 = (f3>=0.f)?f3:LEAKY_ACT*f3;
        float f4 = bf_lo(raw.z)*sb.x + hb.x; f4 = (f4>=0.f)?f4:LEAKY_ACT*f4;
        float f5 = bf_hi(raw.z)*sb.y + hb.y; f5 = (f5>=0.f)?f5:LEAKY_ACT*f5;
        float f6 = bf_lo(raw.w)*sb.z + hb.z; f6 = (f6>=0.f)?f6:LEAKY_ACT*f6;
        float f7 = bf_hi(raw.w)*sb.w + hb.w; f7 = (f7>=0.f)?f7:LEAKY_ACT*f7;
        raw.x = (unsigned)f2bf(f0) | ((unsigned)f2bf(f1) << 16);
        raw.y = (unsigned)f2bf(f2) | ((unsigned)f2bf(f3) << 16);
        raw.z = (unsigned)f2bf(f4) | ((unsigned)f2bf(f5) << 16);
        raw.w = (unsigned)f2bf(f6) | ((unsigned)f2bf(f7) << 16);
      }
    }
    *reinterpret_cast<uint4*>(&As[srow][sseg]) = raw;
    __syncthreads();
    bf16x8 a = *reinterpret_cast<const bf16x8*>(&As[arow][koff]);
    #pragma unroll
    for (int nt = 0; nt < 8; ++nt){
      int ncol = n0 + nt*16 + (lane & 15);
      bf16x8 b = *reinterpret_cast<const bf16x8*>(&Wt[(size_t)ncol*K + k0 + koff]);
      acc[nt] = __builtin_amdgcn_mfma_f32_16x16x32_bf16(a, b, acc[nt], 0, 0, 0);
    }
  }
  int rbase = m0 + wv*16 + (lane >> 4)*4;
  #pragma unroll
  for (int nt = 0; nt < 8; ++nt){
    int col = n0 + nt*16 + (lane & 15);
    float bv = bias[col];
    #pragma unroll
    for (int r = 0; r < 4; ++r){
      int row = rbase + r;
      if (row < N){
        float v = acc[nt][r] + bv;
        if (isL) xlb[(size_t)row*C + col] = f2bf(v);
        else     xr [(size_t)row*C + col] = v;
      }
    }
  }
}

// ---------------- fused GATv2: logits + softmax + aggregation ---------------
// 4 waves/block (each wave owns its own nodes); triple-buffered edge batches.
// f16-packed We with v_dot2 matvec; self-loop ea-mean in-flight; DPP logit
// reduce; no max-subtraction (logits O(1) by construction). BN stats NOT
// fused (R13: same-address atomic flood).
template<int C, int UNR, bool OUTBF>
__global__ __launch_bounds__(256) void k_gat_fused(
    const int* __restrict__ rowptr, const int2* __restrict__ csr2,
    const float* __restrict__ edge_attr,
    const unsigned short* __restrict__ xlb, const float* __restrict__ xr,
    const float* __restrict__ We, const float* __restrict__ att,
    const float* __restrict__ bias, float* __restrict__ out_f,
    unsigned short* __restrict__ out_b, int E, int N)
{
  constexpr int CPL = C/64;          // 2 or 4 columns per lane
  constexpr int PK  = CPL/2;         // packed uints per edge per lane
  const int wv = threadIdx.x >> 6;
  const int lane = threadIdx.x & 63;
  const int c0 = lane*CPL;

  f16x2 wpk[8][CPL];                 // We pairs (k=2k8,2k8+1) packed f16
  #pragma unroll
  for (int k8 = 0; k8 < 8; ++k8)
    #pragma unroll
    for (int q = 0; q < CPL; ++q)
      wpk[k8][q] = cvtpk(We[(2*k8)*C + c0 + q], We[(2*k8+1)*C + c0 + q]);
  float attv[CPL], biasv[CPL];
  #pragma unroll
  for (int q = 0; q < CPL; ++q){ attv[q] = att[c0 + q]; biasv[q] = bias[c0 + q]; }

  for (int n = blockIdx.x*4 + wv; n < N; n += gridDim.x*4){
    float xrv[CPL];
    #pragma unroll
    for (int q = 0; q < CPL; ++q) xrv[q] = xr[(size_t)n*C + c0 + q];
    int start = __builtin_amdgcn_readfirstlane(rowptr[n]);
    int end   = __builtin_amdgcn_readfirstlane(rowptr[n+1]);

    float denom = 0.f;
    float acc[CPL] = {};
    float2 easum = make_float2(0.f, 0.f);   // per-lane pair (lane&7) sum

    unsigned xA[UNR][PK]; f16x2 eaA[UNR];
    unsigned xB[UNR][PK]; f16x2 eaB[UNR];
    unsigned xC[UNR][PK]; f16x2 eaC[UNR];

    auto stage = [&](int base, unsigned (&xp)[UNR][PK], f16x2 (&eal)[UNR])->int{
      int mask = 0;
      #pragma unroll
      for (int u = 0; u < UNR; ++u){
        bool zero = true;
        if (base + u < end){
          int2 v = csr2[base + u];
          int e = __builtin_amdgcn_readfirstlane(v.y);
          if (e < E){                        // real edge (self slot deferred)
            int s = __builtin_amdgcn_readfirstlane(v.x);
            float2 ep = *reinterpret_cast<const float2*>(
                &edge_attr[(size_t)e*16 + 2*(lane & 7)]);
            easum.x += ep.x; easum.y += ep.y;
            eal[u] = cvtpk(ep.x, ep.y);
            const unsigned short* prow = xlb + (size_t)s*C + c0;
            if constexpr (PK == 2){
              uint2 w = *reinterpret_cast<const uint2*>(prow);
              xp[u][0] = w.x; xp[u][1] = w.y;
            } else {
              xp[u][0] = *reinterpret_cast<const unsigned*>(prow);
            }
            mask |= 1 << u;
            zero = false;
          }
        }
        if (zero){
          eal[u] = cvtpk(0.f, 0.f);
          #pragma unroll
          for (int p = 0; p < PK; ++p) xp[u][p] = 0;
        }
      }
      return mask;
    };
    auto compute = [&](unsigned (&xp)[UNR][PK], f16x2 (&eal)[UNR], int mask){
      float pe[UNR];
      #pragma unroll
      for (int u = 0; u < UNR; ++u){
        if ((mask >> u) & 1){
          float w[CPL] = {};
          #pragma unroll
          for (int k8 = 0; k8 < 8; ++k8){
            f16x2 pr = bcast_pair(eal[u], k8);   // v_readlane broadcast
            #pragma unroll
            for (int q = 0; q < CPL; ++q) w[q] = FDOT2(pr, wpk[k8][q], w[q]);
          }
          float p = 0.f;
          #pragma unroll
          for (int p2 = 0; p2 < PK; ++p2){
            float x0 = bf_lo(xp[u][p2]), x1 = bf_hi(xp[u][p2]);
            float v0 = x0 + xrv[2*p2]   + w[2*p2];
            float v1 = x1 + xrv[2*p2+1] + w[2*p2+1];
            v0 = (v0 >= 0.f) ? v0 : LEAKY_ATT*v0;
            v1 = (v1 >= 0.f) ? v1 : LEAKY_ATT*v1;
            p += attv[2*p2]*v0 + attv[2*p2+1]*v1;
          }
          p = wave_sum64(p);                     // DPP reduce (VALU only)
          pe[u] = __expf(p);
        } else pe[u] = 0.f;
      }
      #pragma unroll
      for (int u = 0; u < UNR; ++u) denom += pe[u];
      #pragma unroll
      for (int u = 0; u < UNR; ++u)
        #pragma unroll
        for (int p2 = 0; p2 < PK; ++p2){
          acc[2*p2]   += pe[u]*bf_lo(xp[u][p2]);
          acc[2*p2+1] += pe[u]*bf_hi(xp[u][p2]);
        }
    };

    // 3-deep software pipeline: while computing batch k, batch k+2 stages.
    int i = start;
    int mA = stage(i, xA, eaA);
    int mB = (i + UNR < end) ? stage(i + UNR, xB, eaB) : 0;
    int mC = 0;
    int s = i + 2*UNR;
    for (;;){
      if (s < end){ mC = stage(s, xC, eaC); s += UNR; } else mC = 0;
      compute(xA, eaA, mA);
      i += UNR; if (i >= end) break;
      if (s < end){ mA = stage(s, xA, eaA); s += UNR; } else mA = 0;
      compute(xB, eaB, mB);
      i += UNR; if (i >= end) break;
      if (s < end){ mB = stage(s, xB, eaB); s += UNR; } else mB = 0;
      compute(xC, eaC, mC);
      i += UNR; if (i >= end) break;
    }

    // self-loop: ea = mean of real in-edge attrs (0 if none), xl row of n
    {
      int deg = end - start - 1;
      float invd = 1.0f / (float)max(deg, 1);
      eaA[0] = cvtpk(easum.x*invd, easum.y*invd);
      const unsigned short* prow = xlb + (size_t)n*C + c0;
      if constexpr (PK == 2){
        uint2 w = *reinterpret_cast<const uint2*>(prow);
        xA[0][0] = w.x; xA[0][1] = w.y;
      } else {
        xA[0][0] = *reinterpret_cast<const unsigned*>(prow);
      }
      compute(xA, eaA, 1);
    }

    float inv = 1.0f / denom;     // self-loop guarantees denom > 0
    if constexpr (OUTBF){
      #pragma unroll
      for (int p2 = 0; p2 < PK; ++p2){
        unsigned po = (unsigned)f2bf(acc[2*p2]*inv + biasv[2*p2])
                    | ((unsigned)f2bf(acc[2*p2+1]*inv + biasv[2*p2+1]) << 16);
        *reinterpret_cast<unsigned*>(&out_b[(size_t)n*C + c0 + 2*p2]) = po;
      }
    } else {
      if constexpr (CPL == 4){
        float4 o = make_float4(acc[0]*inv + biasv[0], acc[1]*inv + biasv[1],
                               acc[2]*inv + biasv[2], acc[3]*inv + biasv[3]);
        *reinterpret_cast<float4*>(&out_f[(size_t)n*C + c0]) = o;
      } else {
        float2 o = make_float2(acc[0]*inv + biasv[0], acc[1]*inv + biasv[1]);
        *reinterpret_cast<float2*>(&out_f[(size_t)n*C + c0]) = o;
      }
    }
  }
}

// ---------------- batchnorm -------------------------------------------------
__global__ void k_bnstats(const float* __restrict__ x, float* __restrict__ sums,
                          int N, int C){
  int c = threadIdx.x;           // blockDim = C
  float s = 0.f, s2 = 0.f;
  for (int r = blockIdx.x; r < N; r += gridDim.x){
    float v = x[(size_t)r*C + c];
    s += v; s2 += v*v;
  }
  atomicAdd(&sums[c], s);
  atomicAdd(&sums[C + c], s2);
}

__global__ void k_bnstats_bf(const unsigned short* __restrict__ x,
                             float* __restrict__ sums, int N, int C){
  int c = threadIdx.x;
  float s = 0.f, s2 = 0.f;
  for (int r = blockIdx.x; r < N; r += gridDim.x){
    float v = bf2f(x[(size_t)r*C + c]);
    s += v; s2 += v*v;
  }
  atomicAdd(&sums[c], s);
  atomicAdd(&sums[C + c], s2);
}

// sums -> per-channel affine (scale, shift)
__global__ void k_bnfin(const float* __restrict__ sums, const float* __restrict__ gam,
                        const float* __restrict__ bet, float* __restrict__ sc,
                        float* __restrict__ sh, int N, int C){
  int c = threadIdx.x; if (c >= C) return;
  float invN = 1.0f / (float)N;
  float mu  = sums[c] * invN;
  float var = sums[C + c] * invN - mu*mu;
  float r = rsqrtf(var + BN_EPS) * gam[c];
  sc[c] = r;
  sh[c] = bet[c] - mu*r;
}

// ------- fused BN-apply + leaky + gate + graph softmax + pooled output ------
// One 1024-thread block (16 waves) per graph. Graph boundaries found by
// per-block binary search over sorted batch (replaces the gptr kernel).
__global__ __launch_bounds__(1024) void k_bngate_final(
    const float* __restrict__ d2, const float* __restrict__ sc2,
    const float* __restrict__ sh2, const float* __restrict__ Wg,
    const float* __restrict__ bg, const int* __restrict__ batch,
    float* __restrict__ out, int N)
{
  __shared__ float lacc[16][256];
  __shared__ float lden[16];
  int g = blockIdx.x;
  // lower_bound(batch, g) and lower_bound(batch, g+1)
  int lo = 0, hi = N;
  while (lo < hi){ int m = (lo+hi) >> 1; if (batch[m] < g) lo = m+1; else hi = m; }
  int s = lo;
  hi = N;
  while (lo < hi){ int m = (lo+hi) >> 1; if (batch[m] < g+1) lo = m+1; else hi = m; }
  int e = lo;

  int tid = threadIdx.x, wv = tid >> 6, lane = tid & 63;
  int c0 = lane*4;
  float4 scv = *reinterpret_cast<const float4*>(&sc2[c0]);
  float4 shv = *reinterpret_cast<const float4*>(&sh2[c0]);
  float4 wgv = *reinterpret_cast<const float4*>(&Wg[c0]);
  float bgv = bg[0];
  float den = 0.f;
  float a0 = 0.f, a1 = 0.f, a2 = 0.f, a3 = 0.f;
  for (int n = s + wv; n < e; n += 16){
    float4 xv = *reinterpret_cast<const float4*>(&d2[(size_t)n*256 + c0]);
    float v0 = xv.x*scv.x + shv.x;  v0 = (v0 >= 0.f) ? v0 : LEAKY_ACT*v0;
    float v1 = xv.y*scv.y + shv.y;  v1 = (v1 >= 0.f) ? v1 : LEAKY_ACT*v1;
    float v2 = xv.z*scv.z + shv.z;  v2 = (v2 >= 0.f) ? v2 : LEAKY_ACT*v2;
    float v3 = xv.w*scv.w + shv.w;  v3 = (v3 >= 0.f) ? v3 : LEAKY_ACT*v3;
    float p = wave_sum64(v0*wgv.x + v1*wgv.y + v2*wgv.z + v3*wgv.w) + bgv;
    float ex = __expf(p);
    den += ex;
    a0 += ex*v0; a1 += ex*v1; a2 += ex*v2; a3 += ex*v3;
  }
  lacc[wv][c0+0] = a0; lacc[wv][c0+1] = a1;
  lacc[wv][c0+2] = a2; lacc[wv][c0+3] = a3;
  if (lane == 0) lden[wv] = den;
  __syncthreads();
  if (tid < 256){
    float at = 0.f, dt = 0.f;
    #pragma unroll
    for (int w = 0; w < 16; ++w){ at += lacc[w][tid]; dt += lden[w]; }
    out[(size_t)g*256 + tid] = (e > s) ? at/dt : 0.f;
  }
}

// ============================================================================
extern "C" void kernel_launch(void* const* d_in, const int* in_sizes, int n_in,
                              void* d_out, int out_size, void* d_ws, size_t ws_size,
                              hipStream_t stream){
  const float* x         = (const float*)d_in[0];
  const int*   edge_idx  = (const int*)  d_in[1];
  const float* edge_attr = (const float*)d_in[2];
  const int*   batch     = (const int*)  d_in[3];
  const float* emb       = (const float*)d_in[4];
  const float* Wl1 = (const float*)d_in[5];  const float* bl1 = (const float*)d_in[6];
  const float* Wr1 = (const float*)d_in[7];  const float* br1 = (const float*)d_in[8];
  const float* We1 = (const float*)d_in[9];  const float* att1= (const float*)d_in[10];
  const float* bias1=(const float*)d_in[11]; const float* g1  = (const float*)d_in[12];
  const float* be1 = (const float*)d_in[13];
  const float* Wl2 = (const float*)d_in[14]; const float* bl2 = (const float*)d_in[15];
  const float* Wr2 = (const float*)d_in[16]; const float* br2 = (const float*)d_in[17];
  const float* We2 = (const float*)d_in[18]; const float* att2= (const float*)d_in[19];
  const float* bias2=(const float*)d_in[20]; const float* g2  = (const float*)d_in[21];
  const float* be2 = (const float*)d_in[22];
  const float* Wg  = (const float*)d_in[23]; const float* bg  = (const float*)d_in[24];
  float* out = (float*)d_out;

  const int N = in_sizes[0] / 64;        // 50000
  const int E = in_sizes[1] / 2;         // 800000
  const int EP = E + N;                  // with self-loops
  const int G = 256;
  const int* srcv = edge_idx;
  const int* dstv = edge_idx + E;

  // ---- workspace layout (element offsets, 64-elem aligned) ----
  float* ws = (float*)d_ws;
  size_t o = 0;
  auto alloc = [&](size_t elems){ size_t r = o; o += (elems + 63) & ~(size_t)63; return r; };
  size_t o_big1  = alloc((size_t)N*128);  // hb (bf16 N*128), later xlb2 (bf16 N*256)
  size_t o_union = alloc((size_t)N*256);  // [xr1 f32 | d1b bf16], later d2 f32
  size_t o_xlb1  = alloc((size_t)N*64);   // xlb1 (bf16, N*128)
  size_t o_xr2   = alloc((size_t)N*256);
  size_t o_bn1   = alloc(2*128);          // bn1+bn2 contiguous -> one memset
  size_t o_bn2   = alloc(2*256);
  size_t o_sc1   = alloc(128);
  size_t o_sh1   = alloc(128);
  size_t o_sc2   = alloc(256);
  size_t o_sh2   = alloc(256);
  size_t o_deg   = alloc((size_t)N);      // deg+cur contiguous -> one memset
  size_t o_cur   = alloc((size_t)N);
  size_t o_rp    = alloc((size_t)N+1);
  size_t o_bsum  = alloc(64);
  size_t o_csr   = alloc((size_t)EP*2);   // int2 per CSR slot
  size_t o_wt1l  = alloc(128*128/2);      // bf16 128x128
  size_t o_wt1r  = alloc(128*128/2);
  size_t o_wt2l  = alloc(256*128/2);      // bf16 256x128
  size_t o_wt2r  = alloc(256*128/2);

  unsigned short* hb   = (unsigned short*)(ws + o_big1);
  unsigned short* xlb2 = (unsigned short*)(ws + o_big1);   // after hb is dead
  float* xr1  = ws + o_union;                              // N*128 f32
  unsigned short* d1b = (unsigned short*)(ws + o_union + (size_t)N*128);
  float* d2   = ws + o_union;                              // after xr1/d1b dead
  unsigned short* xlb1 = (unsigned short*)(ws + o_xlb1);
  float* xr2  = ws + o_xr2;
  float* bn1  = ws + o_bn1;
  float* bn2  = ws + o_bn2;
  float* sc1  = ws + o_sc1;
  float* sh1  = ws + o_sh1;
  float* sc2  = ws + o_sc2;
  float* sh2  = ws + o_sh2;
  int*   deg  = (int*)(ws + o_deg);
  int*   cur  = (int*)(ws + o_cur);
  int*   rp   = (int*)(ws + o_rp);
  int*   bsum = (int*)(ws + o_bsum);
  int2*  csr2 = (int2*)(ws + o_csr);
  unsigned short* wt1l = (unsigned short*)(ws + o_wt1l);
  unsigned short* wt1r = (unsigned short*)(ws + o_wt1r);
  unsigned short* wt2l = (unsigned short*)(ws + o_wt2l);
  unsigned short* wt2r = (unsigned short*)(ws + o_wt2r);

  // ---- zero accumulators (graph replays must be deterministic) ----
  hipMemsetAsync(deg, 0, (o_cur - o_deg + (size_t)N)*4, stream);       // deg+cur
  hipMemsetAsync(bn1, 0, (o_bn2 - o_bn1 + 2*256)*4, stream);           // bn1+bn2

  auto nblk = [](long long n, int b){ return (int)((n + b - 1) / b); };

  // ---- merged prep: embed + deg + wprep (independent jobs, one dispatch) ----
  k_prep<<<1088, 256, 0, stream>>>(x, emb, hb, dstv, deg,
      Wl1, Wr1, Wl2, Wr2, wt1l, wt1r, wt2l, wt2r, N, E);
  int nbs = nblk(N, 1024);
  k_scan1<<<nbs, 256, 0, stream>>>(deg, rp, bsum, N);
  k_scan2<<<1, 64, 0, stream>>>(bsum, nbs);
  k_scan3<<<nblk((long long)N+1,256), 256, 0, stream>>>(rp, bsum, N, EP);
  k_csrfill<<<nblk(EP,256), 256, 0, stream>>>(srcv, dstv, rp, cur, csr2, E, N);

  const int FGRID = 4096;   // 4-wave blocks -> 16384 waves

  // ---- layer 1 (C=128) ----
  {
    dim3 grid(nblk(N,64), 2);            // y=0: xl, y=1: xr
    k_gemm_mfma<false><<<grid, 256, 0, stream>>>(hb, wt1l, bl1, wt1r, br1,
        nullptr, nullptr, xlb1, xr1, N, 128);
  }
  k_gat_fused<128,8,true><<<FGRID, 256, 0, stream>>>(rp, csr2, edge_attr,
      xlb1, xr1, We1, att1, bias1, nullptr, d1b, E, N);
  k_bnstats_bf<<<512, 128, 0, stream>>>(d1b, bn1, N, 128);
  k_bnfin<<<1, 128, 0, stream>>>(bn1, g1, be1, sc1, sh1, N, 128);

  // ---- layer 2 (C=256); layer-1 BN+leaky fused into A-staging ----
  {
    dim3 grid(nblk(N,64), 4);            // y=0,1: xl halves; y=2,3: xr halves
    k_gemm_mfma<true><<<grid, 256, 0, stream>>>(d1b, wt2l, bl2, wt2r, br2,
        sc1, sh1, xlb2, xr2, N, 256);
  }
  k_gat_fused<256,6,false><<<FGRID, 256, 0, stream>>>(rp, csr2, edge_attr,
      xlb2, xr2, We2, att2, bias2, d2, nullptr, E, N);
  k_bnstats<<<512, 256, 0, stream>>>(d2, bn2, N, 256);
  k_bnfin<<<1, 256, 0, stream>>>(bn2, g2, be2, sc2, sh2, N, 256);

  // ---- attentional aggregation (BN-apply on read; boundaries via bsearch) ----
  k_bngate_final<<<G, 1024, 0, stream>>>(d2, sc2, sh2, Wg, bg, batch, out, N);
}

// Round 17
// 739.567 us; speedup vs baseline: 1.0233x; 1.0233x over previous
//
#include <hip/hip_runtime.h>
#include <cstddef>
#include <cstdint>

#define LEAKY_ATT 0.2f
#define LEAKY_ACT 0.01f
#define BN_EPS 1e-5f

typedef __attribute__((ext_vector_type(8))) short bf16x8;
typedef __attribute__((ext_vector_type(4))) float f32x4;
typedef __fp16 f16x2 __attribute__((ext_vector_type(2)));

// round-to-nearest-even f32 -> bf16
static __device__ __forceinline__ unsigned short f2bf(float f){
  unsigned u = __float_as_uint(f);
  unsigned r = u + 0x7fffu + ((u >> 16) & 1u);
  return (unsigned short)(r >> 16);
}
static __device__ __forceinline__ float bf_lo(unsigned u){ return __uint_as_float(u << 16); }
static __device__ __forceinline__ float bf_hi(unsigned u){ return __uint_as_float(u & 0xffff0000u); }
static __device__ __forceinline__ float bf2f(unsigned short u){ return __uint_as_float((unsigned)u << 16); }

static __device__ __forceinline__ f16x2 cvtpk(float a, float b){
#if __has_builtin(__builtin_amdgcn_cvt_pkrtz)
  return __builtin_amdgcn_cvt_pkrtz(a, b);
#else
  f16x2 r; r.x = (__fp16)a; r.y = (__fp16)b; return r;
#endif
}
#if __has_builtin(__builtin_amdgcn_fdot2)
#define FDOT2(a,b,c) __builtin_amdgcn_fdot2((a),(b),(c),false)
#else
static __device__ __forceinline__ float fdot2_emu(f16x2 a, f16x2 b, float c){
  return (float)a.x*(float)b.x + ((float)a.y*(float)b.y + c);
}
#define FDOT2(a,b,c) fdot2_emu((a),(b),(c))
#endif

static __device__ __forceinline__ f16x2 bcast_pair(f16x2 v, int k){
  int iv; __builtin_memcpy(&iv, &v, 4);
  iv = __shfl(iv, k);
  f16x2 r; __builtin_memcpy(&r, &iv, 4);
  return r;
}

// full-wave (64-lane) f32 sum via DPP row ops — VALU pipe only, no LDS.
static __device__ __forceinline__ float wave_sum64(float x){
  float t;
  t = __int_as_float(__builtin_amdgcn_update_dpp(0, __float_as_int(x), 0x111, 0xf, 0xf, true)); x += t;
  t = __int_as_float(__builtin_amdgcn_update_dpp(0, __float_as_int(x), 0x112, 0xf, 0xf, true)); x += t;
  t = __int_as_float(__builtin_amdgcn_update_dpp(0, __float_as_int(x), 0x114, 0xf, 0xf, true)); x += t;
  t = __int_as_float(__builtin_amdgcn_update_dpp(0, __float_as_int(x), 0x118, 0xf, 0xf, true)); x += t;
  t = __int_as_float(__builtin_amdgcn_update_dpp(0, __float_as_int(x), 0x142, 0xf, 0xf, true)); x += t; // row_bcast:15
  t = __int_as_float(__builtin_amdgcn_update_dpp(0, __float_as_int(x), 0x143, 0xf, 0xf, true)); x += t; // row_bcast:31
  return __int_as_float(__builtin_amdgcn_readlane(__float_as_int(x), 63));
}

// ------ merged prep: embed (blocks [0,768)) + deg (768..1024) + wprep -------
__global__ __launch_bounds__(256) void k_prep(
    const float* __restrict__ x, const float* __restrict__ emb,
    unsigned short* __restrict__ hb,
    const int* __restrict__ dst, int* __restrict__ deg,
    const float* __restrict__ Wl1, const float* __restrict__ Wr1,
    const float* __restrict__ Wl2, const float* __restrict__ Wr2,
    unsigned short* __restrict__ wt1l, unsigned short* __restrict__ wt1r,
    unsigned short* __restrict__ wt2l, unsigned short* __restrict__ wt2r,
    int N, int E)
{
  int b = blockIdx.x;
  if (b < 768){                    // ---- embed: argmax + bf16 lookup ----
    int wv = threadIdx.x >> 6, lane = threadIdx.x & 63;
    for (int n = b*4 + wv; n < N; n += 768*4){
      float v = x[(size_t)n*64 + lane];
      int idx = lane;
      #pragma unroll
      for (int off = 32; off; off >>= 1){
        float ov = __shfl_down(v, off);
        int   oi = __shfl_down(idx, off);
        if (ov > v || (ov == v && oi < idx)) { v = ov; idx = oi; }
      }
      idx = __shfl(idx, 0);
      hb[(size_t)n*128 + lane]      = f2bf(emb[(size_t)idx*128 + lane]);
      hb[(size_t)n*128 + 64 + lane] = f2bf(emb[(size_t)idx*128 + 64 + lane]);
    }
  } else if (b < 1024){            // ---- deg ----
    for (int e = (b-768)*256 + threadIdx.x; e < E; e += 256*256)
      atomicAdd(&deg[dst[e]], 1);
  } else {                         // ---- wprep ×4 (bf16 transpose) ----
    const int T1 = 128*128, T2 = 128*256;
    for (int i = (b-1024)*256 + threadIdx.x; i < 2*T1 + 2*T2; i += 64*256){
      int j = i; const float* W; unsigned short* Wt; int K = 128, C;
      if (j < T1)            { W = Wl1; Wt = wt1l; C = 128; }
      else if (j < 2*T1)     { j -= T1;   W = Wr1; Wt = wt1r; C = 128; }
      else if (j < 2*T1+T2)  { j -= 2*T1; W = Wl2; Wt = wt2l; C = 256; }
      else                   { j -= 2*T1+T2; W = Wr2; Wt = wt2r; C = 256; }
      int n = j / K, k = j - n*K;
      Wt[j] = f2bf(W[(size_t)k*C + n]);
    }
  }
}

// ---------------- hierarchical exclusive scan of (deg[i]+1) -----------------
__global__ __launch_bounds__(256) void k_scan1(const int* __restrict__ deg,
                        int* __restrict__ rowptr, int* __restrict__ bsum, int N){
  __shared__ int sd[256];
  int tid = threadIdx.x;
  int base = blockIdx.x*1024 + tid*4;
  int v0=0,v1=0,v2=0,v3=0;
  if (base+0 < N) v0 = deg[base+0]+1;
  if (base+1 < N) v1 = deg[base+1]+1;
  if (base+2 < N) v2 = deg[base+2]+1;
  if (base+3 < N) v3 = deg[base+3]+1;
  int t = v0+v1+v2+v3;
  sd[tid] = t;
  __syncthreads();
  for (int off = 1; off < 256; off <<= 1){
    int x = (tid >= off) ? sd[tid-off] : 0;
    __syncthreads();
    sd[tid] += x;
    __syncthreads();
  }
  int excl = sd[tid] - t;
  if (tid == 255) bsum[blockIdx.x] = sd[255];
  if (base+0 < N) rowptr[base+0] = excl;
  if (base+1 < N) rowptr[base+1] = excl + v0;
  if (base+2 < N) rowptr[base+2] = excl + v0 + v1;
  if (base+3 < N) rowptr[base+3] = excl + v0 + v1 + v2;
}
__global__ void k_scan2(int* __restrict__ bsum, int nb){
  int lane = threadIdx.x & 63;
  int carry = 0;
  for (int base = 0; base < nb; base += 64){
    int idx = base + lane;
    int v = (idx < nb) ? bsum[idx] : 0;
    int orig = v;
    #pragma unroll
    for (int off = 1; off < 64; off <<= 1){
      int x = __shfl_up(v, off);
      if (lane >= off) v += x;
    }
    if (idx < nb) bsum[idx] = carry + v - orig;   // exclusive
    carry += __shfl(v, 63);
  }
}
__global__ void k_scan3(int* __restrict__ rowptr, const int* __restrict__ bsum,
                        int N, int EP){
  int i = blockIdx.x*blockDim.x + threadIdx.x;
  if (i < N) rowptr[i] += bsum[i >> 10];
  if (i == N) rowptr[N] = EP;
}

// ---------------- CSR fill: store {src, edge_id} per slot -------------------
__global__ void k_csrfill(const int* __restrict__ src, const int* __restrict__ dst,
                          const int* __restrict__ rowptr,
                          int* __restrict__ cur, int2* __restrict__ csr2, int E, int N){
  int i = blockIdx.x*blockDim.x + threadIdx.x;
  if (i >= E + N) return;
  int d, s;
  if (i < E){ d = dst[i]; s = src[i]; }
  else      { d = i - E;  s = i - E;  }
  int pos = atomicAdd(&cur[d], 1);
  csr2[rowptr[d] + pos] = make_int2(s, i);
}

// ---------------- MFMA GEMM: [xl|xr] = A[N,128]bf16 @ Wt^T + bias -----------
template<bool APPLY_BN>
__global__ __launch_bounds__(256) void k_gemm_mfma(
    const unsigned short* __restrict__ A,
    const unsigned short* __restrict__ Wtl, const float* __restrict__ bl,
    const unsigned short* __restrict__ Wtr, const float* __restrict__ br,
    const float* __restrict__ bnsc, const float* __restrict__ bnsh,
    unsigned short* __restrict__ xlb, float* __restrict__ xr,
    int N, int C)
{
  constexpr int K = 128;
  __shared__ unsigned short As[64][40];    // +8 bf16 pad: bank-conflict-free b128
  int tid = threadIdx.x;
  int wv = tid >> 6, lane = tid & 63;
  int m0 = blockIdx.x*64;
  int half = gridDim.y >> 1;
  bool isL = ((int)blockIdx.y < half);
  int n0 = (isL ? blockIdx.y : blockIdx.y - half) * 128;
  const unsigned short* Wt = isL ? Wtl : Wtr;
  const float* bias = isL ? bl : br;

  f32x4 acc[8];
  #pragma unroll
  for (int t = 0; t < 8; ++t) acc[t] = (f32x4){0.f,0.f,0.f,0.f};

  int srow = tid >> 2;            // 0..63
  int sseg = (tid & 3) * 8;       // k-offset 0,8,16,24
  int grow = m0 + srow;
  int arow = wv*16 + (lane & 15);
  int koff = (lane >> 4) * 8;

  for (int k0 = 0; k0 < K; k0 += 32){
    __syncthreads();
    uint4 raw = make_uint4(0,0,0,0);
    if (grow < N){
      raw = *reinterpret_cast<const uint4*>(&A[(size_t)grow*K + k0 + sseg]);
      if constexpr (APPLY_BN){
        float4 sa = *reinterpret_cast<const float4*>(&bnsc[k0 + sseg]);
        float4 sb = *reinterpret_cast<const float4*>(&bnsc[k0 + sseg + 4]);
        float4 ha = *reinterpret_cast<const float4*>(&bnsh[k0 + sseg]);
        float4 hb = *reinterpret_cast<const float4*>(&bnsh[k0 + sseg + 4]);
        float f0 = bf_lo(raw.x)*sa.x + ha.x; f0 = (f0>=0.f)?f0:LEAKY_ACT*f0;
        float f1 = bf_hi(raw.x)*sa.y + ha.y; f1 = (f1>=0.f)?f1:LEAKY_ACT*f1;
        float f2 = bf_lo(raw.y)*sa.z + ha.z; f2 = (f2>=0.f)?f2:LEAKY_ACT*f2;
        float f3 = bf_hi(raw.y)*sa.w + ha.w; f3 = (f3>=0.f)?f3:LEAKY_ACT*f3;
        float f4 = bf_lo(raw.z)*sb.x + hb.x; f4 = (f4>=0.f)?f4:LEAKY_ACT*f4;
        float f5 = bf_hi(raw.z)*sb.y + hb.y; f5 = (f5>=0.f)?f5:LEAKY_ACT*f5;
        float f6 = bf_lo(raw.w)*sb.z + hb.z; f6 = (f6>=0.f)?f6:LEAKY_ACT*f6;
        float f7 = bf_hi(raw.w)*sb.w + hb.w; f7 = (f7>=0.f)?f7:LEAKY_ACT*f7;
        raw.x = (unsigned)f2bf(f0) | ((unsigned)f2bf(f1) << 16);
        raw.y = (unsigned)f2bf(f2) | ((unsigned)f2bf(f3) << 16);
        raw.z = (unsigned)f2bf(f4) | ((unsigned)f2bf(f5) << 16);
        raw.w = (unsigned)f2bf(f6) | ((unsigned)f2bf(f7) << 16);
      }
    }
    *reinterpret_cast<uint4*>(&As[srow][sseg]) = raw;
    __syncthreads();
    bf16x8 a = *reinterpret_cast<const bf16x8*>(&As[arow][koff]);
    #pragma unroll
    for (int nt = 0; nt < 8; ++nt){
      int ncol = n0 + nt*16 + (lane & 15);
      bf16x8 b = *reinterpret_cast<const bf16x8*>(&Wt[(size_t)ncol*K + k0 + koff]);
      acc[nt] = __builtin_amdgcn_mfma_f32_16x16x32_bf16(a, b, acc[nt], 0, 0, 0);
    }
  }
  int rbase = m0 + wv*16 + (lane >> 4)*4;
  #pragma unroll
  for (int nt = 0; nt < 8; ++nt){
    int col = n0 + nt*16 + (lane & 15);
    float bv = bias[col];
    #pragma unroll
    for (int r = 0; r < 4; ++r){
      int row = rbase + r;
      if (row < N){
        float v = acc[nt][r] + bv;
        if (isL) xlb[(size_t)row*C + col] = f2bf(v);
        else     xr [(size_t)row*C + col] = v;
      }
    }
  }
}

// ---------------- fused GATv2: logits + softmax + aggregation ---------------
// 2 waves/block (R15-verified best: finer block granularity beats 4-wave,
// R16 regression), triple-buffered edge batches; f16-packed We with v_dot2
// matvec; self-loop ea-mean in-flight; DPP logit reduce; no max-subtraction
// (logits O(1) by construction). BN stats NOT fused (R13 atomic flood).
template<int C, int UNR, bool OUTBF>
__global__ __launch_bounds__(128) void k_gat_fused(
    const int* __restrict__ rowptr, const int2* __restrict__ csr2,
    const float* __restrict__ edge_attr,
    const unsigned short* __restrict__ xlb, const float* __restrict__ xr,
    const float* __restrict__ We, const float* __restrict__ att,
    const float* __restrict__ bias, float* __restrict__ out_f,
    unsigned short* __restrict__ out_b, int E, int N)
{
  constexpr int CPL = C/64;          // 2 or 4 columns per lane
  constexpr int PK  = CPL/2;         // packed uints per edge per lane
  const int wv = threadIdx.x >> 6;
  const int lane = threadIdx.x & 63;
  const int c0 = lane*CPL;

  f16x2 wpk[8][CPL];                 // We pairs (k=2k8,2k8+1) packed f16
  #pragma unroll
  for (int k8 = 0; k8 < 8; ++k8)
    #pragma unroll
    for (int q = 0; q < CPL; ++q)
      wpk[k8][q] = cvtpk(We[(2*k8)*C + c0 + q], We[(2*k8+1)*C + c0 + q]);
  float attv[CPL], biasv[CPL];
  #pragma unroll
  for (int q = 0; q < CPL; ++q){ attv[q] = att[c0 + q]; biasv[q] = bias[c0 + q]; }

  for (int n = blockIdx.x*2 + wv; n < N; n += gridDim.x*2){
    float xrv[CPL];
    #pragma unroll
    for (int q = 0; q < CPL; ++q) xrv[q] = xr[(size_t)n*C + c0 + q];
    int start = __builtin_amdgcn_readfirstlane(rowptr[n]);
    int end   = __builtin_amdgcn_readfirstlane(rowptr[n+1]);

    float denom = 0.f;
    float acc[CPL] = {};
    float2 easum = make_float2(0.f, 0.f);   // per-lane pair (lane&7) sum

    unsigned xA[UNR][PK]; f16x2 eaA[UNR];
    unsigned xB[UNR][PK]; f16x2 eaB[UNR];
    unsigned xC[UNR][PK]; f16x2 eaC[UNR];

    auto stage = [&](int base, unsigned (&xp)[UNR][PK], f16x2 (&eal)[UNR])->int{
      int mask = 0;
      #pragma unroll
      for (int u = 0; u < UNR; ++u){
        bool zero = true;
        if (base + u < end){
          int2 v = csr2[base + u];
          int e = __builtin_amdgcn_readfirstlane(v.y);
          if (e < E){                        // real edge (self slot deferred)
            int s = __builtin_amdgcn_readfirstlane(v.x);
            float2 ep = *reinterpret_cast<const float2*>(
                &edge_attr[(size_t)e*16 + 2*(lane & 7)]);
            easum.x += ep.x; easum.y += ep.y;
            eal[u] = cvtpk(ep.x, ep.y);
            const unsigned short* prow = xlb + (size_t)s*C + c0;
            if constexpr (PK == 2){
              uint2 w = *reinterpret_cast<const uint2*>(prow);
              xp[u][0] = w.x; xp[u][1] = w.y;
            } else {
              xp[u][0] = *reinterpret_cast<const unsigned*>(prow);
            }
            mask |= 1 << u;
            zero = false;
          }
        }
        if (zero){
          eal[u] = cvtpk(0.f, 0.f);
          #pragma unroll
          for (int p = 0; p < PK; ++p) xp[u][p] = 0;
        }
      }
      return mask;
    };
    auto compute = [&](unsigned (&xp)[UNR][PK], f16x2 (&eal)[UNR], int mask){
      float pe[UNR];
      #pragma unroll
      for (int u = 0; u < UNR; ++u){
        if ((mask >> u) & 1){
          float w[CPL] = {};
          #pragma unroll
          for (int k8 = 0; k8 < 8; ++k8){
            f16x2 pr = bcast_pair(eal[u], k8);   // v_readlane broadcast
            #pragma unroll
            for (int q = 0; q < CPL; ++q) w[q] = FDOT2(pr, wpk[k8][q], w[q]);
          }
          float p = 0.f;
          #pragma unroll
          for (int p2 = 0; p2 < PK; ++p2){
            float x0 = bf_lo(xp[u][p2]), x1 = bf_hi(xp[u][p2]);
            float v0 = x0 + xrv[2*p2]   + w[2*p2];
            float v1 = x1 + xrv[2*p2+1] + w[2*p2+1];
            v0 = (v0 >= 0.f) ? v0 : LEAKY_ATT*v0;
            v1 = (v1 >= 0.f) ? v1 : LEAKY_ATT*v1;
            p += attv[2*p2]*v0 + attv[2*p2+1]*v1;
          }
          p = wave_sum64(p);                     // DPP reduce (VALU only)
          pe[u] = __expf(p);
        } else pe[u] = 0.f;
      }
      #pragma unroll
      for (int u = 0; u < UNR; ++u) denom += pe[u];
      #pragma unroll
      for (int u = 0; u < UNR; ++u)
        #pragma unroll
        for (int p2 = 0; p2 < PK; ++p2){
          acc[2*p2]   += pe[u]*bf_lo(xp[u][p2]);
          acc[2*p2+1] += pe[u]*bf_hi(xp[u][p2]);
        }
    };

    // 3-deep software pipeline: while computing batch k, batch k+2 stages.
    int i = start;
    int mA = stage(i, xA, eaA);
    int mB = (i + UNR < end) ? stage(i + UNR, xB, eaB) : 0;
    int mC = 0;
    int s = i + 2*UNR;
    for (;;){
      if (s < end){ mC = stage(s, xC, eaC); s += UNR; } else mC = 0;
      compute(xA, eaA, mA);
      i += UNR; if (i >= end) break;
      if (s < end){ mA = stage(s, xA, eaA); s += UNR; } else mA = 0;
      compute(xB, eaB, mB);
      i += UNR; if (i >= end) break;
      if (s < end){ mB = stage(s, xB, eaB); s += UNR; } else mB = 0;
      compute(xC, eaC, mC);
      i += UNR; if (i >= end) break;
    }

    // self-loop: ea = mean of real in-edge attrs (0 if none), xl row of n
    {
      int deg = end - start - 1;
      float invd = 1.0f / (float)max(deg, 1);
      eaA[0] = cvtpk(easum.x*invd, easum.y*invd);
      const unsigned short* prow = xlb + (size_t)n*C + c0;
      if constexpr (PK == 2){
        uint2 w = *reinterpret_cast<const uint2*>(prow);
        xA[0][0] = w.x; xA[0][1] = w.y;
      } else {
        xA[0][0] = *reinterpret_cast<const unsigned*>(prow);
      }
      compute(xA, eaA, 1);
    }

    float inv = 1.0f / denom;     // self-loop guarantees denom > 0
    if constexpr (OUTBF){
      #pragma unroll
      for (int p2 = 0; p2 < PK; ++p2){
        unsigned po = (unsigned)f2bf(acc[2*p2]*inv + biasv[2*p2])
                    | ((unsigned)f2bf(acc[2*p2+1]*inv + biasv[2*p2+1]) << 16);
        *reinterpret_cast<unsigned*>(&out_b[(size_t)n*C + c0 + 2*p2]) = po;
      }
    } else {
      if constexpr (CPL == 4){
        float4 o = make_float4(acc[0]*inv + biasv[0], acc[1]*inv + biasv[1],
                               acc[2]*inv + biasv[2], acc[3]*inv + biasv[3]);
        *reinterpret_cast<float4*>(&out_f[(size_t)n*C + c0]) = o;
      } else {
        float2 o = make_float2(acc[0]*inv + biasv[0], acc[1]*inv + biasv[1]);
        *reinterpret_cast<float2*>(&out_f[(size_t)n*C + c0]) = o;
      }
    }
  }
}

// ---------------- batchnorm -------------------------------------------------
__global__ void k_bnstats(const float* __restrict__ x, float* __restrict__ sums,
                          int N, int C){
  int c = threadIdx.x;           // blockDim = C
  float s = 0.f, s2 = 0.f;
  for (int r = blockIdx.x; r < N; r += gridDim.x){
    float v = x[(size_t)r*C + c];
    s += v; s2 += v*v;
  }
  atomicAdd(&sums[c], s);
  atomicAdd(&sums[C + c], s2);
}

__global__ void k_bnstats_bf(const unsigned short* __restrict__ x,
                             float* __restrict__ sums, int N, int C){
  int c = threadIdx.x;
  float s = 0.f, s2 = 0.f;
  for (int r = blockIdx.x; r < N; r += gridDim.x){
    float v = bf2f(x[(size_t)r*C + c]);
    s += v; s2 += v*v;
  }
  atomicAdd(&sums[c], s);
  atomicAdd(&sums[C + c], s2);
}

// sums -> per-channel affine (scale, shift)
__global__ void k_bnfin(const float* __restrict__ sums, const float* __restrict__ gam,
                        const float* __restrict__ bet, float* __restrict__ sc,
                        float* __restrict__ sh, int N, int C){
  int c = threadIdx.x; if (c >= C) return;
  float invN = 1.0f / (float)N;
  float mu  = sums[c] * invN;
  float var = sums[C + c] * invN - mu*mu;
  float r = rsqrtf(var + BN_EPS) * gam[c];
  sc[c] = r;
  sh[c] = bet[c] - mu*r;
}

// ------- fused BN-apply + leaky + gate + graph softmax + pooled output ------
// One 1024-thread block (16 waves) per graph; boundaries via binary search.
__global__ __launch_bounds__(1024) void k_bngate_final(
    const float* __restrict__ d2, const float* __restrict__ sc2,
    const float* __restrict__ sh2, const float* __restrict__ Wg,
    const float* __restrict__ bg, const int* __restrict__ batch,
    float* __restrict__ out, int N)
{
  __shared__ float lacc[16][256];
  __shared__ float lden[16];
  int g = blockIdx.x;
  int lo = 0, hi = N;
  while (lo < hi){ int m = (lo+hi) >> 1; if (batch[m] < g) lo = m+1; else hi = m; }
  int s = lo;
  hi = N;
  while (lo < hi){ int m = (lo+hi) >> 1; if (batch[m] < g+1) lo = m+1; else hi = m; }
  int e = lo;

  int tid = threadIdx.x, wv = tid >> 6, lane = tid & 63;
  int c0 = lane*4;
  float4 scv = *reinterpret_cast<const float4*>(&sc2[c0]);
  float4 shv = *reinterpret_cast<const float4*>(&sh2[c0]);
  float4 wgv = *reinterpret_cast<const float4*>(&Wg[c0]);
  float bgv = bg[0];
  float den = 0.f;
  float a0 = 0.f, a1 = 0.f, a2 = 0.f, a3 = 0.f;
  for (int n = s + wv; n < e; n += 16){
    float4 xv = *reinterpret_cast<const float4*>(&d2[(size_t)n*256 + c0]);
    float v0 = xv.x*scv.x + shv.x;  v0 = (v0 >= 0.f) ? v0 : LEAKY_ACT*v0;
    float v1 = xv.y*scv.y + shv.y;  v1 = (v1 >= 0.f) ? v1 : LEAKY_ACT*v1;
    float v2 = xv.z*scv.z + shv.z;  v2 = (v2 >= 0.f) ? v2 : LEAKY_ACT*v2;
    float v3 = xv.w*scv.w + shv.w;  v3 = (v3 >= 0.f) ? v3 : LEAKY_ACT*v3;
    float p = wave_sum64(v0*wgv.x + v1*wgv.y + v2*wgv.z + v3*wgv.w) + bgv;
    float ex = __expf(p);
    den += ex;
    a0 += ex*v0; a1 += ex*v1; a2 += ex*v2; a3 += ex*v3;
  }
  lacc[wv][c0+0] = a0; lacc[wv][c0+1] = a1;
  lacc[wv][c0+2] = a2; lacc[wv][c0+3] = a3;
  if (lane == 0) lden[wv] = den;
  __syncthreads();
  if (tid < 256){
    float at = 0.f, dt = 0.f;
    #pragma unroll
    for (int w = 0; w < 16; ++w){ at += lacc[w][tid]; dt += lden[w]; }
    out[(size_t)g*256 + tid] = (e > s) ? at/dt : 0.f;
  }
}

// ============================================================================
extern "C" void kernel_launch(void* const* d_in, const int* in_sizes, int n_in,
                              void* d_out, int out_size, void* d_ws, size_t ws_size,
                              hipStream_t stream){
  const float* x         = (const float*)d_in[0];
  const int*   edge_idx  = (const int*)  d_in[1];
  const float* edge_attr = (const float*)d_in[2];
  const int*   batch     = (const int*)  d_in[3];
  const float* emb       = (const float*)d_in[4];
  const float* Wl1 = (const float*)d_in[5];  const float* bl1 = (const float*)d_in[6];
  const float* Wr1 = (const float*)d_in[7];  const float* br1 = (const float*)d_in[8];
  const float* We1 = (const float*)d_in[9];  const float* att1= (const float*)d_in[10];
  const float* bias1=(const float*)d_in[11]; const float* g1  = (const float*)d_in[12];
  const float* be1 = (const float*)d_in[13];
  const float* Wl2 = (const float*)d_in[14]; const float* bl2 = (const float*)d_in[15];
  const float* Wr2 = (const float*)d_in[16]; const float* br2 = (const float*)d_in[17];
  const float* We2 = (const float*)d_in[18]; const float* att2= (const float*)d_in[19];
  const float* bias2=(const float*)d_in[20]; const float* g2  = (const float*)d_in[21];
  const float* be2 = (const float*)d_in[22];
  const float* Wg  = (const float*)d_in[23]; const float* bg  = (const float*)d_in[24];
  float* out = (float*)d_out;

  const int N = in_sizes[0] / 64;        // 50000
  const int E = in_sizes[1] / 2;         // 800000
  const int EP = E + N;                  // with self-loops
  const int G = 256;
  const int* srcv = edge_idx;
  const int* dstv = edge_idx + E;

  // ---- workspace layout (element offsets, 64-elem aligned) ----
  float* ws = (float*)d_ws;
  size_t o = 0;
  auto alloc = [&](size_t elems){ size_t r = o; o += (elems + 63) & ~(size_t)63; return r; };
  size_t o_big1  = alloc((size_t)N*128);  // hb (bf16 N*128), later xlb2 (bf16 N*256)
  size_t o_union = alloc((size_t)N*256);  // [xr1 f32 | d1b bf16], later d2 f32
  size_t o_xlb1  = alloc((size_t)N*64);   // xlb1 (bf16, N*128)
  size_t o_xr2   = alloc((size_t)N*256);
  size_t o_bn1   = alloc(2*128);          // bn1+bn2 contiguous -> one memset
  size_t o_bn2   = alloc(2*256);
  size_t o_sc1   = alloc(128);
  size_t o_sh1   = alloc(128);
  size_t o_sc2   = alloc(256);
  size_t o_sh2   = alloc(256);
  size_t o_deg   = alloc((size_t)N);      // deg+cur contiguous -> one memset
  size_t o_cur   = alloc((size_t)N);
  size_t o_rp    = alloc((size_t)N+1);
  size_t o_bsum  = alloc(64);
  size_t o_csr   = alloc((size_t)EP*2);   // int2 per CSR slot
  size_t o_wt1l  = alloc(128*128/2);      // bf16 128x128
  size_t o_wt1r  = alloc(128*128/2);
  size_t o_wt2l  = alloc(256*128/2);      // bf16 256x128
  size_t o_wt2r  = alloc(256*128/2);

  unsigned short* hb   = (unsigned short*)(ws + o_big1);
  unsigned short* xlb2 = (unsigned short*)(ws + o_big1);   // after hb is dead
  float* xr1  = ws + o_union;                              // N*128 f32
  unsigned short* d1b = (unsigned short*)(ws + o_union + (size_t)N*128);
  float* d2   = ws + o_union;                              // after xr1/d1b dead
  unsigned short* xlb1 = (unsigned short*)(ws + o_xlb1);
  float* xr2  = ws + o_xr2;
  float* bn1  = ws + o_bn1;
  float* bn2  = ws + o_bn2;
  float* sc1  = ws + o_sc1;
  float* sh1  = ws + o_sh1;
  float* sc2  = ws + o_sc2;
  float* sh2  = ws + o_sh2;
  int*   deg  = (int*)(ws + o_deg);
  int*   cur  = (int*)(ws + o_cur);
  int*   rp   = (int*)(ws + o_rp);
  int*   bsum = (int*)(ws + o_bsum);
  int2*  csr2 = (int2*)(ws + o_csr);
  unsigned short* wt1l = (unsigned short*)(ws + o_wt1l);
  unsigned short* wt1r = (unsigned short*)(ws + o_wt1r);
  unsigned short* wt2l = (unsigned short*)(ws + o_wt2l);
  unsigned short* wt2r = (unsigned short*)(ws + o_wt2r);

  // ---- zero accumulators (graph replays must be deterministic) ----
  hipMemsetAsync(deg, 0, (o_cur - o_deg + (size_t)N)*4, stream);       // deg+cur
  hipMemsetAsync(bn1, 0, (o_bn2 - o_bn1 + 2*256)*4, stream);           // bn1+bn2

  auto nblk = [](long long n, int b){ return (int)((n + b - 1) / b); };

  // ---- merged prep: embed + deg + wprep (independent jobs, one dispatch) ----
  k_prep<<<1088, 256, 0, stream>>>(x, emb, hb, dstv, deg,
      Wl1, Wr1, Wl2, Wr2, wt1l, wt1r, wt2l, wt2r, N, E);
  int nbs = nblk(N, 1024);
  k_scan1<<<nbs, 256, 0, stream>>>(deg, rp, bsum, N);
  k_scan2<<<1, 64, 0, stream>>>(bsum, nbs);
  k_scan3<<<nblk((long long)N+1,256), 256, 0, stream>>>(rp, bsum, N, EP);
  k_csrfill<<<nblk(EP,256), 256, 0, stream>>>(srcv, dstv, rp, cur, csr2, E, N);

  const int FGRID = 8192;   // 2-wave blocks -> 16384 waves (R15-verified)

  // ---- layer 1 (C=128) ----
  {
    dim3 grid(nblk(N,64), 2);            // y=0: xl, y=1: xr
    k_gemm_mfma<false><<<grid, 256, 0, stream>>>(hb, wt1l, bl1, wt1r, br1,
        nullptr, nullptr, xlb1, xr1, N, 128);
  }
  k_gat_fused<128,8,true><<<FGRID, 128, 0, stream>>>(rp, csr2, edge_attr,
      xlb1, xr1, We1, att1, bias1, nullptr, d1b, E, N);
  k_bnstats_bf<<<512, 128, 0, stream>>>(d1b, bn1, N, 128);
  k_bnfin<<<1, 128, 0, stream>>>(bn1, g1, be1, sc1, sh1, N, 128);

  // ---- layer 2 (C=256); layer-1 BN+leaky fused into A-staging ----
  {
    dim3 grid(nblk(N,64), 4);            // y=0,1: xl halves; y=2,3: xr halves
    k_gemm_mfma<true><<<grid, 256, 0, stream>>>(d1b, wt2l, bl2, wt2r, br2,
        sc1, sh1, xlb2, xr2, N, 256);
  }
  k_gat_fused<256,6,false><<<FGRID, 128, 0, stream>>>(rp, csr2, edge_attr,
      xlb2, xr2, We2, att2, bias2, d2, nullptr, E, N);
  k_bnstats<<<512, 256, 0, stream>>>(d2, bn2, N, 256);
  k_bnfin<<<1, 256, 0, stream>>>(bn2, g2, be2, sc2, sh2, N, 256);

  // ---- attentional aggregation (BN-apply on read; boundaries via bsearch) ----
  k_bngate_final<<<G, 1024, 0, stream>>>(d2, sc2, sh2, Wg, bg, batch, out, N);
}